// Round 13
// baseline (355.060 us; speedup 1.0000x reference)
//
#include <hip/hip_runtime.h>
#include <stdint.h>

typedef _Float16 f16;
typedef _Float16 f16x8 __attribute__((ext_vector_type(8)));
typedef _Float16 f16x4 __attribute__((ext_vector_type(4)));
typedef float f32x4 __attribute__((ext_vector_type(4)));

#define GAS __attribute__((address_space(1)))
#define LAS __attribute__((address_space(3)))

// async global->LDS, 16 B per lane; LDS dest = wave-uniform base + lane*16
__device__ __forceinline__ void gl_lds16(const void* g, void* l) {
    __builtin_amdgcn_global_load_lds((const GAS uint32_t*)g, (LAS uint32_t*)l, 16, 0, 0);
}

// Fused preamble (one dispatch): blocks [0, nbzc) zero stats+zrow and cvt
// x->f16 (4/thread); blocks [nbzc, nbzc+2700) transpose the 6 weight tensors
// fp32 [27][Cin][Cout] -> f16 [27][Cout][Cin] via 32x32 LDS tiles (coalesced
// reads/writes, +1 pad -> no bank conflicts; round-10 verified).
__global__ __launch_bounds__(256) void prep(
    const float* __restrict__ x, f16* __restrict__ xh, long nx4,
    const float* __restrict__ ws1, f16* __restrict__ w1,
    const float* __restrict__ w11, f16* __restrict__ wa1,
    const float* __restrict__ w12, f16* __restrict__ wa2,
    const float* __restrict__ w21, f16* __restrict__ wb1,
    const float* __restrict__ w22, f16* __restrict__ wb2,
    const float* __restrict__ ws2, f16* __restrict__ w2,
    float* __restrict__ zbuf, long nz, int nbzc) {
    if ((int)blockIdx.x < nbzc) {
        long t = (long)blockIdx.x * 256 + threadIdx.x;
        if (t < nz) { zbuf[t] = 0.f; return; }
        t -= nz;
        if (t < nx4) {                   // cvt16, 4 elems/thread
            float4 v = ((const float4*)x)[t];
            f16x4 o = {(f16)v.x, (f16)v.y, (f16)v.z, (f16)v.w};
            *(f16x4*)(xh + t * 4) = o;
        }
        return;
    }
    int tau = blockIdx.x - nbzc;         // transpose tile id, [0, 2700)
    const float* src; f16* dst; int Cin, Cout;
    if (tau < 864)        { src = ws1; dst = w1;  Cin = 256; Cout = 128; }
    else if (tau < 1296)  { tau -= 864;  src = w11; dst = wa1; Cin = 128; Cout = 128; }
    else if (tau < 1728)  { tau -= 1296; src = w12; dst = wa2; Cin = 128; Cout = 128; }
    else if (tau < 2160)  { tau -= 1728; src = w21; dst = wb1; Cin = 128; Cout = 128; }
    else if (tau < 2592)  { tau -= 2160; src = w22; dst = wb2; Cin = 128; Cout = 128; }
    else                  { tau -= 2592; src = ws2; dst = w2;  Cin = 128; Cout = 32; }
    const int nci = Cin >> 5, nco = Cout >> 5;
    const int k  = tau / (nci * nco);
    const int rm = tau - k * nci * nco;
    const int ci0 = (rm / nco) << 5;
    const int co0 = (rm % nco) << 5;
    __shared__ float tile[32][33];
    const int r = threadIdx.x >> 5, c = threadIdx.x & 31;
#pragma unroll
    for (int i2 = 0; i2 < 4; i2++)
        tile[r + 8 * i2][c] =
            src[((long)(k * Cin + ci0 + r + 8 * i2)) * Cout + co0 + c];
    __syncthreads();
#pragma unroll
    for (int i2 = 0; i2 < 4; i2++)
        dst[((long)(k * Cout + co0 + r + 8 * i2)) * Cin + ci0 + c] =
            (f16)tile[c][r + 8 * i2];
}

// Dense implicit 3x3x3 conv, f16 raw out, producer-BN FOLD (round-11) and
// WRITEACT (round-12) both verified.
//  LAYER 0/1: round-2 core — A halo slab double-buffered per z-stage, B panel
//  double-buffered per TAP, per-tap __syncthreads (structure measured optimal
//  over 7 attacks; per-tap barrier is LDS-budget-irreducible here).
//  LAYER 2 (round-13): PLANE-GROUP schedule — B panels are 8 KB, so a whole
//  z-plane (9 panels, 72 KB) + A slab (46 KB) fits in 118 KB. Per plane:
//  stage A + all 9 B panels, ONE drain barrier, then 9 taps with ZERO
//  barriers (all buffers read-only). Boundary uses the R6/8/9-verified
//  reload pattern. Removes the ~2-2.5k cy/tap barrier rendezvous that round-5
//  (free-drain) and round-12 (half-traffic, same cost) isolated as the fixed
//  per-tap overhead. Heavy-planes-first remap (R3) so the 360-256 tail is all
//  S=1 blocks.
//  512 threads = 8 waves = 2 waves/SIMD, r2/c2/k2 split; K-halves summed via
//  LDS park in dead buffers; kh==0 waves write + fused BN-stats atomics.
// LAYER 0: CIN=256 (2 halves, 1 in-plane, dz=1-p), COUT=128, grid 216
// LAYER 1: CIN=128, 3 in-planes, j=p+dz,   COUT=128, grid 216
// LAYER 2: CIN=128, 3 in-planes, j=p+dz-1, COUT=32,  grid 360
template <int LAYER, bool FOLD, bool RESID, bool WRITEACT>
__global__ __launch_bounds__(512, 2) void conv_dense(
    const f16* __restrict__ fin, const f16* __restrict__ wt,
    const f16* __restrict__ zrow, f16* __restrict__ out,
    float* __restrict__ stats,
    const float* __restrict__ pstats, const float* __restrict__ pg,
    const float* __restrict__ pb, const f16* __restrict__ resid,
    f16* __restrict__ actout, float pinv) {
    constexpr int COUT = (LAYER == 2) ? 32 : 128;
    constexpr int INRB = (LAYER == 0) ? 512 : 256;   // input row bytes
    constexpr int WRB  = (LAYER == 0) ? 512 : 256;   // weight row bytes per col
    constexpr int RT   = (COUT == 128) ? 4 : 2;      // 16-row tiles per wave
    constexpr int CT   = (COUT == 128) ? 4 : 2;      // 16-col tiles per wave
    constexpr int NBCH = COUT / 4;                   // B chunks (1 KB each)
    constexpr int BPAN = COUT * 256;                 // B panel bytes
    extern __shared__ char smem[];
    // LAYER 0/1: A0 | A1 | B0 | B1.   LAYER 2: A | B[9].
    char* ldsA0 = smem;                 // 46080
    char* ldsA1 = smem + 46080;
    char* ldsB  = smem + ((LAYER == 2) ? 46080 : 92160);

    int b = blockIdx.x;
    if (LAYER == 2) {                   // heavy planes dispatch first (perf only)
        const int order[5] = {2, 1, 3, 0, 4};
        b = order[b / 72] * 72 + (b % 72);
    }
    const int p = b / 72;               // out plane
    const int t0 = b % 72;
    const int y0 = (t0 / 6) * 8;
    const int x0 = (t0 % 6) * 16;
    const int tid = threadIdx.x;
    const int lane = tid & 63;
    const int wave = tid >> 6;          // 0..7
    const int kh = wave & 1;            // K-half: kk in {2kh, 2kh+1}
    const int pairId = wave >> 1;       // 0..3 output-tile group
    const int q = lane >> 4;
    const int r16 = lane & 15;
    const int wr = ((COUT == 128) ? (pairId >> 1) : pairId) * (RT * 16);
    const int wc = ((COUT == 128) ? (pairId & 1) : 0) * (CT * 16);

    // stage list (block-uniform): z-planes (and channel halves for LAYER 0)
    int S = 0;
    int js[3], dzs[3], hs[3];
    if (LAYER == 0) {
        js[0] = 0; dzs[0] = 1 - p; hs[0] = 0;
        js[1] = 0; dzs[1] = 1 - p; hs[1] = 1;
        S = 2;
    } else {
        for (int dz = -1; dz <= 1; dz++) {
            int j = (LAYER == 1) ? p + dz : p + dz - 1;
            if (0 <= j && j < 3) { js[S] = j; dzs[S] = dz; hs[S] = 0; S++; }
        }
    }

    // Producer BN constants for the fold: channels r16*8+e, fixed per lane.
    float psc[8], pbt[8];
    if (FOLD) {
#pragma unroll
        for (int e = 0; e < 8; e++) {
            int c = r16 * 8 + e;
            float mu = pstats[c] * pinv;
            float var = fmaxf(pstats[128 + c] * pinv - mu * mu, 0.f);
            float s = pg[c] * rsqrtf(var + 1e-5f);
            psc[e] = s;
            pbt[e] = pb[c] - mu * s;
        }
    }

    auto stageA = [&](int s, char* buf) {
        const int j = js[s], h = hs[s];
        const long pbase = (long)j * 9216;
        for (int ch = wave; ch < 45; ch += 8) {
            int site = ch * 4 + q;
            int sy = site / 18;
            int sx = site - sy * 18;
            int y = y0 - 1 + sy;
            int x = x0 - 1 + sx;
            bool ok = ((unsigned)y < 96u) & ((unsigned)x < 96u);
            if (FOLD) {
                // reg-stage: raw f16 -> BN+(resid)+ReLU -> swizzled ds_write
                f16x8 o = {};
                if (ok) {
                    const long ro = (pbase + y * 96 + x) * 128 + r16 * 8;
                    f16x8 v = *(const f16x8*)(fin + ro);
                    f16x8 rv = {};
                    if (RESID) rv = *(const f16x8*)(resid + ro);
#pragma unroll
                    for (int e = 0; e < 8; e++) {
                        float t = (float)v[e] * psc[e] + pbt[e];
                        if (RESID) t += (float)rv[e];
                        o[e] = (f16)fmaxf(t, 0.f);
                    }
                    // Owner write: materialize the activated tensor (exactly
                    // one block owns each (plane, y, x) site).
                    if (WRITEACT && j == p &&
                        (unsigned)(sy - 1) < 8u && (unsigned)(sx - 1) < 16u)
                        *(f16x8*)(actout + ro) = o;
                }
                *(f16x8*)(buf + site * 256 + ((r16 ^ (site & 7)) << 4)) = o;
            } else {
                int cc = r16 ^ (site & 7);
                const char* src = ok
                    ? (const char*)fin + (pbase + y * 96 + x) * INRB + h * 256 + cc * 16
                    : (const char*)zrow + cc * 16;
                gl_lds16(src, buf + ch * 1024);
            }
        }
    };
    auto stageB = [&](int k, int h, char* buf) {
        for (int ch = wave; ch < NBCH; ch += 8) {
            int col = ch * 4 + q;
            int cc = r16 ^ (col & 7);
            const char* src = (const char*)wt + (long)(k * COUT + col) * WRB +
                              h * 256 + cc * 16;
            gl_lds16(src, buf + ch * 1024);
        }
    };

    f32x4 acc[RT][CT];
#pragma unroll
    for (int tr = 0; tr < RT; tr++)
#pragma unroll
        for (int c = 0; c < CT; c++) acc[tr][c] = f32x4{0.f, 0.f, 0.f, 0.f};

    if constexpr (LAYER == 2) {
        // PLANE-GROUP schedule: stage whole plane (A + 9 B panels), one drain
        // barrier, 9 barrier-free taps.
        for (int s = 0; s < S; s++) {
            if (s > 0) __syncthreads();      // all reads of plane s-1 done
            stageA(s, ldsA0);
            const int kbase = (dzs[s] + 1) * 9;
#pragma unroll
            for (int i = 0; i < 9; i++) stageB(kbase + i, 0, ldsB + i * BPAN);
            __syncthreads();                 // per-wave vm/lgkm drained + rendezvous
#pragma unroll
            for (int i = 0; i < 9; i++) {
                const char* bufB = ldsB + i * BPAN;
                const int dy = i / 3 - 1, dx = i % 3 - 1;
#pragma unroll
                for (int kk2 = 0; kk2 < 2; kk2++) {
                    const int kk = kh * 2 + kk2;
                    f16x8 Af[RT], Bf[CT];
#pragma unroll
                    for (int tr = 0; tr < RT; tr++) {
                        int site = (wr / 16 + tr + 1 + dy) * 18 + 1 + dx + r16;
                        Af[tr] = *(const f16x8*)(ldsA0 + site * 256 +
                                                 (((kk * 4 + q) ^ (site & 7)) << 4));
                    }
#pragma unroll
                    for (int c = 0; c < CT; c++) {
                        int col = wc + c * 16 + r16;
                        Bf[c] = *(const f16x8*)(bufB + col * 256 +
                                                (((kk * 4 + q) ^ (col & 7)) << 4));
                    }
#pragma unroll
                    for (int tr = 0; tr < RT; tr++)
#pragma unroll
                        for (int c = 0; c < CT; c++)
                            acc[tr][c] = __builtin_amdgcn_mfma_f32_16x16x32_f16(
                                Af[tr], Bf[c], acc[tr][c], 0, 0, 0);
                }
            }
        }
    } else {
        // Round-2 per-tap schedule (measured optimal for 32 KB panels).
        char* ldsB0 = ldsB;
        char* ldsB1 = ldsB + BPAN;
        stageA(0, ldsA0);
        stageB((dzs[0] + 1) * 9, hs[0], ldsB0);
        int tap = 0;
        for (int s = 0; s < S; s++) {
            const char* bufA = (s & 1) ? ldsA1 : ldsA0;
#pragma unroll
            for (int i = 0; i < 9; i++, tap++) {
                __syncthreads();   // drains DMA + ds_writes for tap (+A stage when due)
                if (i == 0 && s + 1 < S) stageA(s + 1, ((s + 1) & 1) ? ldsA1 : ldsA0);
                if (tap + 1 < S * 9) {
                    int sn = (i == 8) ? s + 1 : s;
                    int in2 = (i == 8) ? 0 : i + 1;
                    stageB((dzs[sn] + 1) * 9 + in2, hs[sn],
                           ((tap + 1) & 1) ? ldsB1 : ldsB0);
                }
                const char* bufB = (tap & 1) ? ldsB1 : ldsB0;
                const int dy = i / 3 - 1, dx = i % 3 - 1;
#pragma unroll
                for (int kk2 = 0; kk2 < 2; kk2++) {
                    const int kk = kh * 2 + kk2;
                    f16x8 Af[RT], Bf[CT];
#pragma unroll
                    for (int tr = 0; tr < RT; tr++) {
                        int site = (wr / 16 + tr + 1 + dy) * 18 + 1 + dx + r16;
                        Af[tr] = *(const f16x8*)(bufA + site * 256 +
                                                 (((kk * 4 + q) ^ (site & 7)) << 4));
                    }
#pragma unroll
                    for (int c = 0; c < CT; c++) {
                        int col = wc + c * 16 + r16;
                        Bf[c] = *(const f16x8*)(bufB + col * 256 +
                                                (((kk * 4 + q) ^ (col & 7)) << 4));
                    }
#pragma unroll
                    for (int tr = 0; tr < RT; tr++)
#pragma unroll
                        for (int c = 0; c < CT; c++)
                            acc[tr][c] = __builtin_amdgcn_mfma_f32_16x16x32_f16(
                                Af[tr], Bf[c], acc[tr][c], 0, 0, 0);
                }
            }
        }
    }

    // K-half reduction: kh=1 waves park partials in dead LDS (B buffers for
    // L0/L1: 64 KB; A slab for L2: 46 KB >= 16 KB), kh=0 waves add them.
    char* xch = (LAYER == 2) ? smem : smem + 92160;
    constexpr int XR = RT * CT * 1024;
    __syncthreads();                                 // all tap LDS reads done
    if (kh == 1) {
#pragma unroll
        for (int tr = 0; tr < RT; tr++)
#pragma unroll
            for (int c = 0; c < CT; c++)
                *(f32x4*)(xch + pairId * XR + (tr * CT + c) * 1024 + lane * 16) =
                    acc[tr][c];
    }
    __syncthreads();
    if (kh == 1) return;                             // no barriers past this point
#pragma unroll
    for (int tr = 0; tr < RT; tr++)
#pragma unroll
        for (int c = 0; c < CT; c++)
            acc[tr][c] += *(const f32x4*)(xch + pairId * XR + (tr * CT + c) * 1024 +
                                          lane * 16);

    // Epilogue: write raw f16 + fused BN-stats atomics (stats from fp32 acc).
    const long mbase = (long)p * 9216 + (long)y0 * 96 + x0;
#pragma unroll
    for (int c = 0; c < CT; c++) {
        const int col = wc + c * 16 + r16;
        float sum = 0.f, ssq = 0.f;
#pragma unroll
        for (int tr = 0; tr < RT; tr++) {
            const int ly = wr / 16 + tr;
#pragma unroll
            for (int r = 0; r < 4; r++) {
                const int lx = q * 4 + r;
                float v = acc[tr][c][r];
                out[(mbase + ly * 96 + lx) * COUT + col] = (f16)v;
                sum += v;
                ssq = fmaf(v, v, ssq);
            }
        }
        sum += __shfl_xor(sum, 16);
        sum += __shfl_xor(sum, 32);
        ssq += __shfl_xor(ssq, 16);
        ssq += __shfl_xor(ssq, 32);
        if (q == 0) {
            atomicAdd(&stats[col], sum);
            atomicAdd(&stats[COUT + col], ssq);
        }
    }
}

// BN(train) + ReLU, 8 f16 elems/thread (final layer only).
__global__ __launch_bounds__(256) void bn_apply8(
    const f16x8* __restrict__ f, const float* __restrict__ sums,
    const float* __restrict__ g, const float* __restrict__ bta,
    float* __restrict__ outf, long n8, int C, float invM) {
    long i = (long)blockIdx.x * 256 + threadIdx.x;
    if (i >= n8) return;
    int col0 = (int)((i * 8) & (C - 1));
    f16x8 v = f[i];
    float ro[8];
#pragma unroll
    for (int j = 0; j < 8; j++) {
        int c = col0 + j;
        float mu = sums[c] * invM;
        float var = sums[C + c] * invM - mu * mu;
        var = fmaxf(var, 0.f);
        float sc = g[c] * rsqrtf(var + 1e-5f);
        ro[j] = fmaxf(((float)v[j] - mu) * sc + bta[c], 0.f);
    }
    *(float4*)(outf + i * 8)     = make_float4(ro[0], ro[1], ro[2], ro[3]);
    *(float4*)(outf + i * 8 + 4) = make_float4(ro[4], ro[5], ro[6], ro[7]);
}

extern "C" void kernel_launch(void* const* d_in, const int* in_sizes, int n_in,
                              void* d_out, int out_size, void* d_ws, size_t ws_size,
                              hipStream_t stream) {
    (void)n_in; (void)out_size; (void)ws_size;
    const float* x    = (const float*)d_in[0];
    const float* w_s1 = (const float*)d_in[1];
    const float* g_s1 = (const float*)d_in[2];
    const float* b_s1 = (const float*)d_in[3];
    const float* w11  = (const float*)d_in[4];
    const float* g11  = (const float*)d_in[5];
    const float* b11  = (const float*)d_in[6];
    const float* w12  = (const float*)d_in[7];
    const float* g12  = (const float*)d_in[8];
    const float* b12  = (const float*)d_in[9];
    const float* w21  = (const float*)d_in[10];
    const float* g21  = (const float*)d_in[11];
    const float* b21  = (const float*)d_in[12];
    const float* w22  = (const float*)d_in[13];
    const float* g22  = (const float*)d_in[14];
    const float* b22  = (const float*)d_in[15];
    const float* w_s2 = (const float*)d_in[16];
    const float* g_s2 = (const float*)d_in[17];
    const float* b_s2 = (const float*)d_in[18];

    const int N0 = in_sizes[0] / 256;   // 9216
    const int M1 = in_sizes[19] / 27;   // 27648
    const int M2 = in_sizes[21] / 27;   // 46080

    char* base = (char*)d_ws;
    size_t off = 0;
    auto alloc = [&](size_t bytes) -> char* {
        off = (off + 255) & ~(size_t)255;
        char* p = base + off;
        off += bytes;
        return p;
    };
    f16* xh  = (f16*)alloc((size_t)N0 * 256 * 2);
    f16* w1  = (f16*)alloc(27UL * 128 * 256 * 2);
    f16* wa1 = (f16*)alloc(27UL * 128 * 128 * 2);
    f16* wa2 = (f16*)alloc(27UL * 128 * 128 * 2);
    f16* wb1 = (f16*)alloc(27UL * 128 * 128 * 2);
    f16* wb2 = (f16*)alloc(27UL * 128 * 128 * 2);
    f16* w2  = (f16*)alloc(27UL * 32 * 128 * 2);
    f16* fA  = (f16*)alloc((size_t)M1 * 128 * 2);   // f1 (owner-written by conv11)
    f16* fC  = (f16*)alloc((size_t)M1 * 128 * 2);   // f2 (owner-written by conv21)
    f16* rA  = (f16*)alloc((size_t)M1 * 128 * 2);   // raw rotating
    f16* rB  = (f16*)alloc((size_t)M1 * 128 * 2);   // raw rotating
    f16* rS2 = (f16*)alloc((size_t)M2 * 32 * 2);    // raw final conv out
    float* stats = (float*)alloc(1344UL * 4);       // 6 layers of sum/ssq
    f16*   zrow  = (f16*)alloc(512);                // zero site (256B used)

    const int lds01 = 92160 + 2 * 128 * 256;   // 157696 -> 1 blk/CU
    const int lds2  = 46080 + 9 * 32 * 256;    // 119808 -> 1 blk/CU (plane-group)
    (void)hipFuncSetAttribute((const void*)conv_dense<0, false, false, false>,
                              hipFuncAttributeMaxDynamicSharedMemorySize, lds01);
    (void)hipFuncSetAttribute((const void*)conv_dense<1, true, false, true>,
                              hipFuncAttributeMaxDynamicSharedMemorySize, lds01);
    (void)hipFuncSetAttribute((const void*)conv_dense<1, true, false, false>,
                              hipFuncAttributeMaxDynamicSharedMemorySize, lds01);
    (void)hipFuncSetAttribute((const void*)conv_dense<1, true, true, true>,
                              hipFuncAttributeMaxDynamicSharedMemorySize, lds01);
    (void)hipFuncSetAttribute((const void*)conv_dense<2, true, true, false>,
                              hipFuncAttributeMaxDynamicSharedMemorySize, lds2);

    // Fused preamble: zero stats(1344)+zrow(128) floats, cvt x (4/thread),
    // then 2700 LDS-tiled 32x32 transpose blocks. One dispatch.
    const long nz  = 1472;
    const long nx4 = (long)N0 * 256 / 4;                 // 589824
    const int nbzc = (int)((nz + nx4 + 255) / 256);      // zero+cvt blocks
    prep<<<nbzc + 2700, 256, 0, stream>>>(
        x, xh, nx4, w_s1, w1, w11, wa1, w12, wa2, w21, wb1, w22, wb2,
        w_s2, w2, stats, nz, nbzc);

    const float inv1 = 1.f / (float)M1, inv2 = 1.f / (float)M2;
    const int g1 = 3 * 72;              // 216 blocks
    const int g2 = 5 * 72;              // 360 blocks
    const long n8b = (long)M2 * 32 / 8; // 184320
    const int gb = (int)((n8b + 255) / 256);

    // conv0: xh -> raw rA + stats0
    conv_dense<0, false, false, false><<<g1, 512, lds01, stream>>>(
        xh, w1, zrow, rA, stats, nullptr, nullptr, nullptr, nullptr, nullptr, 0.f);
    // conv11, FOLD(bn0) + WRITEACT(fA): rA -> raw rB + stats11
    conv_dense<1, true, false, true><<<g1, 512, lds01, stream>>>(
        rA, wa1, zrow, rB, stats + 256, stats, g_s1, b_s1, nullptr, fA, inv1);
    // conv12, FOLD(bn11): rB -> raw rA + stats12
    conv_dense<1, true, false, false><<<g1, 512, lds01, stream>>>(
        rB, wa2, zrow, rA, stats + 512, stats + 256, g11, b11, nullptr, nullptr, inv1);
    // conv21, FOLD(bn12) + RESID(fA) + WRITEACT(fC): rA -> raw rB + stats21
    conv_dense<1, true, true, true><<<g1, 512, lds01, stream>>>(
        rA, wb1, zrow, rB, stats + 768, stats + 512, g12, b12, fA, fC, inv1);
    // conv22, FOLD(bn21): rB -> raw rA + stats22
    conv_dense<1, true, false, false><<<g1, 512, lds01, stream>>>(
        rB, wb2, zrow, rA, stats + 1024, stats + 768, g21, b21, nullptr, nullptr, inv1);
    // conv_s2, FOLD(bn22) + RESID(fC): rA -> raw rS2 + statsS2 (plane-group)
    conv_dense<2, true, true, false><<<g2, 512, lds2, stream>>>(
        rA, w2, zrow, rS2, stats + 1280, stats + 1024, g22, b22, fC, nullptr, inv1);
    // final BN (stats not final until conv_s2 completes): rS2 -> d_out (fp32)
    bn_apply8<<<gb, 256, 0, stream>>>((const f16x8*)rS2, stats + 1280, g_s2, b_s2,
                                      (float*)d_out, n8b, 32, inv2);
}